// Round 4
// baseline (1639.631 us; speedup 1.0000x reference)
//
#include <hip/hip_runtime.h>
#include <math.h>

#define BATCH 512
#define TT    1024
#define FF    128
#define UU    50
#define ZN    200          // 4*UU
#define NP    208          // padded N (13 * 16)
#define NT    13           // N tiles of 16
#define MROWS (BATCH * TT) // 524288
#define BM    128          // rows per GEMM block
#define RPP   8            // rows per pass in fallback GEMM
#define RSTRIDE 52         // Rt row stride in floats: 52*4B=208B, i*52%32 tiles all banks

typedef __attribute__((ext_vector_type(8))) short bhalf8;
typedef __attribute__((ext_vector_type(4))) short bhalf4;
typedef __attribute__((ext_vector_type(4))) float f32x4;

__device__ __forceinline__ float sigmoid_fast(float x) {
    return 1.0f / (1.0f + __expf(-x));
}
__device__ __forceinline__ float tanh_fast(float x) {
    float e = __expf(2.0f * x);
    return 1.0f - 2.0f / (e + 1.0f);
}
__device__ __forceinline__ unsigned short bf16_rtn(float x) {
    unsigned int u = __float_as_uint(x);
    unsigned int r = u + 0x7FFFu + ((u >> 16) & 1u);
    return (unsigned short)(r >> 16);
}
__device__ __forceinline__ float bf16_f32(unsigned short h) {
    return __uint_as_float(((unsigned int)h) << 16);
}

// ---------------- Prep: Kt_hi/Kt_lo[NP][FF] bf16 (transposed, hi/lo split) -------
__global__ void prep_kt_kernel(const float* __restrict__ K,
                               unsigned short* __restrict__ kt_hi,
                               unsigned short* __restrict__ kt_lo) {
    const int c = threadIdx.x;          // column 0..255 (c<NP active)
    if (c >= NP) return;
    for (int k = 0; k < FF; ++k) {
        float v = (c < ZN) ? K[k * ZN + c] : 0.0f;
        unsigned short h = bf16_rtn(v);
        float lo = v - bf16_f32(h);
        kt_hi[c * FF + k] = h;
        kt_lo[c * FF + k] = bf16_rtn(lo);
    }
}

// ---------------- Kernel A: zx[m, j] = x[m, :] @ K[:, j] + bias[j] via MFMA ------
// (unchanged from round 3 — verified absmax 1.9e-6)
__launch_bounds__(256, 2)
__global__ void xk_mfma_kernel(const float* __restrict__ x,
                               const unsigned short* __restrict__ kt_hi,
                               const unsigned short* __restrict__ kt_lo,
                               const float* __restrict__ bias,
                               float* __restrict__ zx) {
    __shared__ __align__(16) char xlds[2 * BM * FF * 2];   // hi plane @0, lo @32768

    const int tid = threadIdx.x;
    const size_t rowbase = (size_t)blockIdx.x * BM;
    const float* xb = x + rowbase * FF;

    const float4* gx = (const float4*)xb;
    #pragma unroll
    for (int i = 0; i < 16; ++i) {
        float4 v = gx[tid + 256 * i];
        const int fidx = (tid + 256 * i) * 4;
        const int row = fidx >> 7;
        const int col = fidx & 127;
        unsigned short h0 = bf16_rtn(v.x), h1 = bf16_rtn(v.y),
                       h2 = bf16_rtn(v.z), h3 = bf16_rtn(v.w);
        bhalf4 hv = { (short)h0, (short)h1, (short)h2, (short)h3 };
        bhalf4 lv = { (short)bf16_rtn(v.x - bf16_f32(h0)),
                      (short)bf16_rtn(v.y - bf16_f32(h1)),
                      (short)bf16_rtn(v.z - bf16_f32(h2)),
                      (short)bf16_rtn(v.w - bf16_f32(h3)) };
        const unsigned byte = (unsigned)((row << 8) + (col << 1)) ^ (((unsigned)row & 7u) << 4);
        *(bhalf4*)(xlds + byte)         = hv;
        *(bhalf4*)(xlds + 32768 + byte) = lv;
    }
    __syncthreads();

    const int w = tid >> 6, l = tid & 63;
    const int lrow = l & 15;
    const int lk   = (l >> 4) << 3;

    float bv[NT];
    #pragma unroll
    for (int nt = 0; nt < NT; ++nt) {
        const int cidx = nt * 16 + lrow;
        bv[nt] = (cidx < ZN) ? bias[cidx] : 0.0f;
    }

    f32x4 acc0[NT], acc1[NT];
    #pragma unroll
    for (int nt = 0; nt < NT; ++nt) { acc0[nt] = (f32x4)0.0f; acc1[nt] = (f32x4)0.0f; }

    #pragma unroll
    for (int ks = 0; ks < 4; ++ks) {
        const int kbyte = (ks * 32 + lk) * 2;
        const int row0 = (w << 5) + lrow;
        const int row1 = row0 + 16;
        const unsigned b0 = (unsigned)((row0 << 8) + kbyte) ^ (((unsigned)row0 & 7u) << 4);
        const unsigned b1 = (unsigned)((row1 << 8) + kbyte) ^ (((unsigned)row1 & 7u) << 4);
        bhalf8 aH0 = *(const bhalf8*)(xlds + b0);
        bhalf8 aL0 = *(const bhalf8*)(xlds + 32768 + b0);
        bhalf8 aH1 = *(const bhalf8*)(xlds + b1);
        bhalf8 aL1 = *(const bhalf8*)(xlds + 32768 + b1);
        #pragma unroll
        for (int nt = 0; nt < NT; ++nt) {
            const int col = nt * 16 + lrow;
            const size_t koff = ((size_t)col << 7) + (size_t)(ks * 32 + lk);
            bhalf8 bH = *(const bhalf8*)(kt_hi + koff);
            bhalf8 bL = *(const bhalf8*)(kt_lo + koff);
            acc0[nt] = __builtin_amdgcn_mfma_f32_16x16x32_bf16(aH0, bH, acc0[nt], 0, 0, 0);
            acc0[nt] = __builtin_amdgcn_mfma_f32_16x16x32_bf16(aH0, bL, acc0[nt], 0, 0, 0);
            acc0[nt] = __builtin_amdgcn_mfma_f32_16x16x32_bf16(aL0, bH, acc0[nt], 0, 0, 0);
            acc1[nt] = __builtin_amdgcn_mfma_f32_16x16x32_bf16(aH1, bH, acc1[nt], 0, 0, 0);
            acc1[nt] = __builtin_amdgcn_mfma_f32_16x16x32_bf16(aH1, bL, acc1[nt], 0, 0, 0);
            acc1[nt] = __builtin_amdgcn_mfma_f32_16x16x32_bf16(aL1, bH, acc1[nt], 0, 0, 0);
        }
    }

    const int rsub = (l >> 4) << 2;
    #pragma unroll
    for (int nt = 0; nt < NT; ++nt) {
        const int col = nt * 16 + lrow;
        if (col < ZN) {
            #pragma unroll
            for (int r = 0; r < 4; ++r) {
                const size_t grow0 = rowbase + (w << 5) + rsub + r;
                zx[grow0 * ZN + col] = acc0[nt][r] + bv[nt];
                const size_t grow1 = grow0 + 16;
                zx[grow1 * ZN + col] = acc1[nt][r] + bv[nt];
            }
        }
    }
}

// ---------------- Kernel B: sequential scan, R resident in LDS -------------------
// Rt[c][k] = R[k][c], row stride 52 floats (208 B): lane i base bank = i*20 mod 32
// tiles all eight 4-aligned bank slots per 8 lanes -> conflict-free ds_read_b128.
#define LSTM_STEP(V, CUR) do {                                                      \
    if (l < UU) {                                                                   \
        float zi = zs[CUR][l];                                                      \
        float zf = zs[CUR][l + UU];                                                 \
        float zg = zs[CUR][l + 2 * UU];                                             \
        float zo = zs[CUR][l + 3 * UU];                                             \
        float gi = sigmoid_fast(zi);                                                \
        float gf = sigmoid_fast(zf);                                                \
        float go = sigmoid_fast(zo);                                                \
        float gg = tanh_fast(zg);                                                   \
        c = gf * c + gi * gg;                                                       \
        hs[w][l] = go * tanh_fast(c);                                               \
    }                                                                               \
    if (tid < ZN) {                                                                 \
        float a0 = (V), a1 = 0.0f, a2 = 0.0f, a3 = 0.0f;                            \
        const float4* h4 = (const float4*)hs[w];                                    \
        const float4* rp = (const float4*)&Rt[(size_t)tid * RSTRIDE];               \
        _Pragma("unroll")                                                           \
        for (int k4 = 0; k4 < 13; ++k4) {                                           \
            float4 hv = h4[k4];                                                     \
            float4 rv = rp[k4];                                                     \
            a0 = fmaf(hv.x, rv.x, a0);                                              \
            a1 = fmaf(hv.y, rv.y, a1);                                              \
            a2 = fmaf(hv.z, rv.z, a2);                                              \
            a3 = fmaf(hv.w, rv.w, a3);                                              \
        }                                                                           \
        zs[(CUR) ^ 1][tid] = (a0 + a1) + (a2 + a3);                                 \
    }                                                                               \
    __syncthreads();                                                                \
} while (0)

__launch_bounds__(256, 2)
__global__ void lstm_scan_kernel(const float* __restrict__ zx,
                                 const float* __restrict__ R,
                                 const float* __restrict__ dw,
                                 const float* __restrict__ db,
                                 float* __restrict__ out) {
    const int b = blockIdx.x;
    const int tid = threadIdx.x;
    const int w = tid >> 6;
    const int l = tid & 63;

    __shared__ __align__(16) float Rt[ZN * RSTRIDE];   // 41600 B
    __shared__ __align__(16) float zs[2][ZN];
    __shared__ __align__(16) float hs[4][56];

    // stage R -> Rt (transposed): coalesced global reads, scattered LDS writes
    for (int idx = tid; idx < UU * ZN; idx += 256) {
        const int k = idx / ZN;          // row in R (0..49)
        const int cc = idx - k * ZN;     // column (0..199)
        Rt[(size_t)cc * RSTRIDE + k] = R[idx];
    }
    if (tid < ZN) { Rt[(size_t)tid * RSTRIDE + 50] = 0.0f; Rt[(size_t)tid * RSTRIDE + 51] = 0.0f; }

    const float* zp = zx + (size_t)b * TT * ZN;
    if (tid < ZN) zs[0][tid] = zp[tid];          // z(0) = zx(0)
    if (l < 56) hs[w][l] = 0.0f;
    float c = 0.0f;
    __syncthreads();

    // 8-deep prefetch pipeline: pipe[i] holds zx(s) for upcoming steps
    float pipe[8];
    #pragma unroll
    for (int i = 0; i < 8; ++i)
        pipe[i] = (tid < ZN) ? zp[(size_t)(1 + i) * ZN + tid] : 0.0f;

    for (int g = 0; g < 127; ++g) {
        #pragma unroll
        for (int q = 0; q < 8; ++q) {
            const int s = (g << 3) + 1 + q;
            float v = pipe[q];
            int sn = s + 8; if (sn > TT - 1) sn = TT - 1;
            if (tid < ZN) pipe[q] = zp[(size_t)sn * ZN + tid];
            LSTM_STEP(v, (q & 1));
        }
    }
    {
        float v;
        v = pipe[0]; LSTM_STEP(v, 0);
        v = pipe[1]; LSTM_STEP(v, 1);
        v = pipe[2]; LSTM_STEP(v, 0);
        v = pipe[3]; LSTM_STEP(v, 1);
        v = pipe[4]; LSTM_STEP(v, 0);
        v = pipe[5]; LSTM_STEP(v, 1);
        v = pipe[6]; LSTM_STEP(v, 0);
    }

    // epilogue: gates of z(1023) (in zs[1]) + dense head, wave 0 only
    if (w == 0) {
        if (l < UU) {
            float zi = zs[1][l];
            float zf = zs[1][l + UU];
            float zg = zs[1][l + 2 * UU];
            float zo = zs[1][l + 3 * UU];
            float gi = sigmoid_fast(zi);
            float gf = sigmoid_fast(zf);
            float go = sigmoid_fast(zo);
            float gg = tanh_fast(zg);
            c = gf * c + gi * gg;
            hs[0][l] = go * tanh_fast(c);
        }
        if (l == 0) {
            float s = db[0];
            for (int u = 0; u < UU; ++u) s = fmaf(hs[0][u], dw[u], s);
            out[b] = s;
        }
    }
}

// ---------------- Fallback GEMM (round-2, slow but correct) ----------------------
__launch_bounds__(256, 1)
__global__ void xk_gemm_kernel(const float* __restrict__ x,
                               const float* __restrict__ K,
                               const float* __restrict__ bias,
                               float* __restrict__ zx) {
    const int b = blockIdx.x;
    const int j = threadIdx.x;

    __shared__ __align__(16) float xs[2][RPP * FF];

    float kreg[FF];
    float bj = 0.0f;
    if (j < ZN) {
        #pragma unroll
        for (int k = 0; k < FF; ++k) kreg[k] = K[k * ZN + j];
        bj = bias[j];
    }

    const float* xrow = x + (size_t)b * TT * FF;
    float* zrow = zx + (size_t)b * TT * ZN;

    ((float4*)xs[0])[threadIdx.x] = ((const float4*)xrow)[threadIdx.x];
    __syncthreads();

    const int NPASS = TT / RPP;
    for (int p = 0; p < NPASS; ++p) {
        const int cur = p & 1, nxt = cur ^ 1;
        float4 gxv;
        const bool more = (p + 1) < NPASS;
        if (more) gxv = ((const float4*)(xrow + (size_t)(p + 1) * RPP * FF))[threadIdx.x];

        if (j < ZN) {
            float acc[RPP];
            #pragma unroll
            for (int r = 0; r < RPP; ++r) acc[r] = bj;
            const float4* xb4 = (const float4*)xs[cur];
            #pragma unroll
            for (int k4 = 0; k4 < FF / 4; ++k4) {
                #pragma unroll
                for (int r = 0; r < RPP; ++r) {
                    float4 xv = xb4[r * (FF / 4) + k4];
                    acc[r] = fmaf(xv.x, kreg[4 * k4 + 0], acc[r]);
                    acc[r] = fmaf(xv.y, kreg[4 * k4 + 1], acc[r]);
                    acc[r] = fmaf(xv.z, kreg[4 * k4 + 2], acc[r]);
                    acc[r] = fmaf(xv.w, kreg[4 * k4 + 3], acc[r]);
                }
            }
            float* zpo = zrow + (size_t)p * RPP * ZN + j;
            #pragma unroll
            for (int r = 0; r < RPP; ++r) zpo[r * ZN] = acc[r];
        }
        if (more) ((float4*)xs[nxt])[threadIdx.x] = gxv;
        __syncthreads();
    }
}

extern "C" void kernel_launch(void* const* d_in, const int* in_sizes, int n_in,
                              void* d_out, int out_size, void* d_ws, size_t ws_size,
                              hipStream_t stream) {
    const float* x    = (const float*)d_in[0];  // [512,1024,128]
    const float* K    = (const float*)d_in[1];  // [128,200]
    const float* R    = (const float*)d_in[2];  // [50,200]
    const float* bias = (const float*)d_in[3];  // [200]
    const float* dw   = (const float*)d_in[4];  // [50,1]
    const float* db   = (const float*)d_in[5];  // [1]
    float* out = (float*)d_out;                 // [512,1]

    const size_t zx_bytes = (size_t)MROWS * ZN * sizeof(float);          // 419.43 MB
    const size_t kt_elems = (size_t)NP * FF;                             // 26624
    const size_t kt_bytes = kt_elems * sizeof(unsigned short);           // 53248

    if (ws_size >= zx_bytes + 2 * kt_bytes) {
        float* zx = (float*)d_ws;
        unsigned short* kt_hi = (unsigned short*)((char*)d_ws + zx_bytes);
        unsigned short* kt_lo = kt_hi + kt_elems;
        prep_kt_kernel<<<1, 256, 0, stream>>>(K, kt_hi, kt_lo);
        xk_mfma_kernel<<<MROWS / BM, 256, 0, stream>>>(x, kt_hi, kt_lo, bias, zx);
        lstm_scan_kernel<<<BATCH, 256, 0, stream>>>(zx, R, dw, db, out);
    } else if (ws_size >= zx_bytes) {
        float* zx = (float*)d_ws;
        xk_gemm_kernel<<<BATCH, 256, 0, stream>>>(x, K, bias, zx);
        lstm_scan_kernel<<<BATCH, 256, 0, stream>>>(zx, R, dw, db, out);
    }
}

// Round 5
// 1174.643 us; speedup vs baseline: 1.3959x; 1.3959x over previous
//
#include <hip/hip_runtime.h>
#include <math.h>

#define BATCH 512
#define TT    1024
#define FF    128
#define UU    50
#define ZN    200          // 4*UU
#define NP    208          // padded N (13 * 16)
#define NT    13           // N tiles of 16
#define MROWS (BATCH * TT) // 524288
#define BM    128          // rows per GEMM block
#define RPP   8            // rows per pass in fallback GEMM
#define RSTRIDE 52         // Rt row stride in floats (208 B, conflict-free b128)

typedef __attribute__((ext_vector_type(8))) short bhalf8;
typedef __attribute__((ext_vector_type(4))) short bhalf4;
typedef __attribute__((ext_vector_type(4))) float f32x4;

__device__ __forceinline__ float sigmoid_fast(float x) {
    return 1.0f / (1.0f + __expf(-x));
}
__device__ __forceinline__ float tanh_fast(float x) {
    float e = __expf(2.0f * x);
    return 1.0f - 2.0f / (e + 1.0f);
}
__device__ __forceinline__ unsigned short bf16_rtn(float x) {
    unsigned int u = __float_as_uint(x);
    unsigned int r = u + 0x7FFFu + ((u >> 16) & 1u);
    return (unsigned short)(r >> 16);
}
__device__ __forceinline__ float bf16_f32(unsigned short h) {
    return __uint_as_float(((unsigned int)h) << 16);
}

// ---------------- Prep: Kt_hi/Kt_lo[NP][FF] bf16 (transposed, hi/lo split) -------
__global__ void prep_kt_kernel(const float* __restrict__ K,
                               unsigned short* __restrict__ kt_hi,
                               unsigned short* __restrict__ kt_lo) {
    const int c = threadIdx.x;
    if (c >= NP) return;
    for (int k = 0; k < FF; ++k) {
        float v = (c < ZN) ? K[k * ZN + c] : 0.0f;
        unsigned short h = bf16_rtn(v);
        float lo = v - bf16_f32(h);
        kt_hi[c * FF + k] = h;
        kt_lo[c * FF + k] = bf16_rtn(lo);
    }
}

// ---------------- Kernel A: zx = x @ K + bias via bf16x2-split MFMA --------------
// (unchanged from round 3 — verified absmax 1.9e-6, ~300 us)
__launch_bounds__(256, 2)
__global__ void xk_mfma_kernel(const float* __restrict__ x,
                               const unsigned short* __restrict__ kt_hi,
                               const unsigned short* __restrict__ kt_lo,
                               const float* __restrict__ bias,
                               float* __restrict__ zx) {
    __shared__ __align__(16) char xlds[2 * BM * FF * 2];

    const int tid = threadIdx.x;
    const size_t rowbase = (size_t)blockIdx.x * BM;
    const float* xb = x + rowbase * FF;

    const float4* gx = (const float4*)xb;
    #pragma unroll
    for (int i = 0; i < 16; ++i) {
        float4 v = gx[tid + 256 * i];
        const int fidx = (tid + 256 * i) * 4;
        const int row = fidx >> 7;
        const int col = fidx & 127;
        unsigned short h0 = bf16_rtn(v.x), h1 = bf16_rtn(v.y),
                       h2 = bf16_rtn(v.z), h3 = bf16_rtn(v.w);
        bhalf4 hv = { (short)h0, (short)h1, (short)h2, (short)h3 };
        bhalf4 lv = { (short)bf16_rtn(v.x - bf16_f32(h0)),
                      (short)bf16_rtn(v.y - bf16_f32(h1)),
                      (short)bf16_rtn(v.z - bf16_f32(h2)),
                      (short)bf16_rtn(v.w - bf16_f32(h3)) };
        const unsigned byte = (unsigned)((row << 8) + (col << 1)) ^ (((unsigned)row & 7u) << 4);
        *(bhalf4*)(xlds + byte)         = hv;
        *(bhalf4*)(xlds + 32768 + byte) = lv;
    }
    __syncthreads();

    const int w = tid >> 6, l = tid & 63;
    const int lrow = l & 15;
    const int lk   = (l >> 4) << 3;

    float bv[NT];
    #pragma unroll
    for (int nt = 0; nt < NT; ++nt) {
        const int cidx = nt * 16 + lrow;
        bv[nt] = (cidx < ZN) ? bias[cidx] : 0.0f;
    }

    f32x4 acc0[NT], acc1[NT];
    #pragma unroll
    for (int nt = 0; nt < NT; ++nt) { acc0[nt] = (f32x4)0.0f; acc1[nt] = (f32x4)0.0f; }

    #pragma unroll
    for (int ks = 0; ks < 4; ++ks) {
        const int kbyte = (ks * 32 + lk) * 2;
        const int row0 = (w << 5) + lrow;
        const int row1 = row0 + 16;
        const unsigned b0 = (unsigned)((row0 << 8) + kbyte) ^ (((unsigned)row0 & 7u) << 4);
        const unsigned b1 = (unsigned)((row1 << 8) + kbyte) ^ (((unsigned)row1 & 7u) << 4);
        bhalf8 aH0 = *(const bhalf8*)(xlds + b0);
        bhalf8 aL0 = *(const bhalf8*)(xlds + 32768 + b0);
        bhalf8 aH1 = *(const bhalf8*)(xlds + b1);
        bhalf8 aL1 = *(const bhalf8*)(xlds + 32768 + b1);
        #pragma unroll
        for (int nt = 0; nt < NT; ++nt) {
            const int col = nt * 16 + lrow;
            const size_t koff = ((size_t)col << 7) + (size_t)(ks * 32 + lk);
            bhalf8 bH = *(const bhalf8*)(kt_hi + koff);
            bhalf8 bL = *(const bhalf8*)(kt_lo + koff);
            acc0[nt] = __builtin_amdgcn_mfma_f32_16x16x32_bf16(aH0, bH, acc0[nt], 0, 0, 0);
            acc0[nt] = __builtin_amdgcn_mfma_f32_16x16x32_bf16(aH0, bL, acc0[nt], 0, 0, 0);
            acc0[nt] = __builtin_amdgcn_mfma_f32_16x16x32_bf16(aL0, bH, acc0[nt], 0, 0, 0);
            acc1[nt] = __builtin_amdgcn_mfma_f32_16x16x32_bf16(aH1, bH, acc1[nt], 0, 0, 0);
            acc1[nt] = __builtin_amdgcn_mfma_f32_16x16x32_bf16(aH1, bL, acc1[nt], 0, 0, 0);
            acc1[nt] = __builtin_amdgcn_mfma_f32_16x16x32_bf16(aL1, bH, acc1[nt], 0, 0, 0);
        }
    }

    const int rsub = (l >> 4) << 2;
    #pragma unroll
    for (int nt = 0; nt < NT; ++nt) {
        const int col = nt * 16 + lrow;
        if (col < ZN) {
            #pragma unroll
            for (int r = 0; r < 4; ++r) {
                const size_t grow0 = rowbase + (w << 5) + rsub + r;
                zx[grow0 * ZN + col] = acc0[nt][r] + bv[nt];
                const size_t grow1 = grow0 + 16;
                zx[grow1 * ZN + col] = acc1[nt][r] + bv[nt];
            }
        }
    }
}

// ---------------- Kernel B: scan, 2 batches per block, R amortized ---------------
// Grid 256 (1/CU). Step = phase A (all waves: z for both batches, one Rt read
// serves 2 batches) / barrier / phase B (wave0 gates b0, wave1 gates b1) / barrier.
// Depth-2 zx prefetch in named registers (no arrays -> no scratch).
__launch_bounds__(256, 1)
__global__ void lstm_scan2_kernel(const float* __restrict__ zx,
                                  const float* __restrict__ R,
                                  const float* __restrict__ dw,
                                  const float* __restrict__ db,
                                  float* __restrict__ out) {
    const int tid = threadIdx.x;
    const int w = tid >> 6;
    const int l = tid & 63;
    const int j = tid;                   // output column (j<200 active in phase A)

    __shared__ __align__(16) float Rt[ZN * RSTRIDE];   // 41600 B
    __shared__ __align__(16) float zsA[ZN];
    __shared__ __align__(16) float zsB[ZN];
    __shared__ __align__(16) float hs[2][56];          // 16B-aligned rows

    // stage R -> Rt (transposed; row stride 52 -> conflict-free b128 reads)
    for (int idx = tid; idx < UU * ZN; idx += 256) {
        const int k = idx / ZN;
        const int cc = idx - k * ZN;
        Rt[(size_t)cc * RSTRIDE + k] = R[idx];
    }
    if (tid < ZN) { Rt[(size_t)tid * RSTRIDE + 50] = 0.0f; Rt[(size_t)tid * RSTRIDE + 51] = 0.0f; }
    if (tid < 2 * 56) ((float*)hs)[tid] = 0.0f;

    const float* zpA = zx + (size_t)(2 * blockIdx.x + 0) * TT * ZN;
    const float* zpB = zx + (size_t)(2 * blockIdx.x + 1) * TT * ZN;

    float cc = 0.0f;                     // cell state (wave0 lanes<50: b0; wave1: b1)

    // preload zx(0), zx(1) for both batches
    float va_a = 0.f, va_b = 0.f, vb_a = 0.f, vb_b = 0.f;
    if (j < ZN) {
        va_a = zpA[j];            va_b = zpB[j];
        vb_a = zpA[ZN + j];       vb_b = zpB[ZN + j];
    }
    __syncthreads();

    #define PHASE_A(VA, VB, T) do {                                                 \
        float na_ = 0.f, nb_ = 0.f;                                                 \
        if (j < ZN) {                                                               \
            const int tn_ = ((T) + 2 < TT) ? (T) + 2 : (TT - 1);                    \
            na_ = zpA[(size_t)tn_ * ZN + j];                                        \
            nb_ = zpB[(size_t)tn_ * ZN + j];                                        \
            float a0 = (VA), a1 = 0.f, b0 = (VB), b1 = 0.f;                         \
            const float4* rp = (const float4*)&Rt[(size_t)j * RSTRIDE];             \
            const float4* h0 = (const float4*)hs[0];                                \
            const float4* h1 = (const float4*)hs[1];                                \
            _Pragma("unroll")                                                       \
            for (int k4 = 0; k4 < 13; ++k4) {                                       \
                float4 rv = rp[k4];                                                 \
                float4 hv0 = h0[k4];                                                \
                float4 hv1 = h1[k4];                                                \
                a0 = fmaf(rv.x, hv0.x, a0); a1 = fmaf(rv.y, hv0.y, a1);             \
                a0 = fmaf(rv.z, hv0.z, a0); a1 = fmaf(rv.w, hv0.w, a1);             \
                b0 = fmaf(rv.x, hv1.x, b0); b1 = fmaf(rv.y, hv1.y, b1);             \
                b0 = fmaf(rv.z, hv1.z, b0); b1 = fmaf(rv.w, hv1.w, b1);             \
            }                                                                       \
            zsA[j] = a0 + a1;                                                       \
            zsB[j] = b0 + b1;                                                       \
        }                                                                           \
        (VA) = na_; (VB) = nb_;                                                     \
    } while (0)

    #define PHASE_B() do {                                                          \
        if (w < 2 && l < UU) {                                                      \
            const float* zrow = (w == 0) ? zsA : zsB;                               \
            float zi = zrow[l];                                                     \
            float zf = zrow[l + UU];                                                \
            float zg = zrow[l + 2 * UU];                                            \
            float zo = zrow[l + 3 * UU];                                            \
            float gi = sigmoid_fast(zi);                                            \
            float gf = sigmoid_fast(zf);                                            \
            float go = sigmoid_fast(zo);                                            \
            float gg = tanh_fast(zg);                                               \
            cc = gf * cc + gi * gg;                                                 \
            hs[w][l] = go * tanh_fast(cc);                                          \
        }                                                                           \
    } while (0)

    for (int t = 0; t < TT; t += 2) {
        // ---- step t (even): consume va_* ----
        PHASE_A(va_a, va_b, t);       // va_* now hold zx(t+2) (wait lands at reuse)
        __syncthreads();
        PHASE_B();
        __syncthreads();
        // ---- step t+1 (odd): consume vb_* ----
        PHASE_A(vb_a, vb_b, t + 1);   // vb_* now hold zx(t+3)
        __syncthreads();
        PHASE_B();
        __syncthreads();
    }

    // epilogue: out = h(1023) . dense_w + dense_b   (wave0 -> b0, wave1 -> b1)
    if (w < 2 && l == 0) {
        float s = db[0];
        #pragma unroll
        for (int u = 0; u < UU; ++u) s = fmaf(hs[w][u], dw[u], s);
        out[2 * blockIdx.x + w] = s;
    }

    #undef PHASE_A
    #undef PHASE_B
}

// ---------------- Fallback GEMM (round-2, slow but correct) ----------------------
__launch_bounds__(256, 1)
__global__ void xk_gemm_kernel(const float* __restrict__ x,
                               const float* __restrict__ K,
                               const float* __restrict__ bias,
                               float* __restrict__ zx) {
    const int b = blockIdx.x;
    const int j = threadIdx.x;

    __shared__ __align__(16) float xs[2][RPP * FF];

    float kreg[FF];
    float bj = 0.0f;
    if (j < ZN) {
        #pragma unroll
        for (int k = 0; k < FF; ++k) kreg[k] = K[k * ZN + j];
        bj = bias[j];
    }

    const float* xrow = x + (size_t)b * TT * FF;
    float* zrow = zx + (size_t)b * TT * ZN;

    ((float4*)xs[0])[threadIdx.x] = ((const float4*)xrow)[threadIdx.x];
    __syncthreads();

    const int NPASS = TT / RPP;
    for (int p = 0; p < NPASS; ++p) {
        const int cur = p & 1, nxt = cur ^ 1;
        float4 gxv;
        const bool more = (p + 1) < NPASS;
        if (more) gxv = ((const float4*)(xrow + (size_t)(p + 1) * RPP * FF))[threadIdx.x];

        if (j < ZN) {
            float acc[RPP];
            #pragma unroll
            for (int r = 0; r < RPP; ++r) acc[r] = bj;
            const float4* xb4 = (const float4*)xs[cur];
            #pragma unroll
            for (int k4 = 0; k4 < FF / 4; ++k4) {
                #pragma unroll
                for (int r = 0; r < RPP; ++r) {
                    float4 xv = xb4[r * (FF / 4) + k4];
                    acc[r] = fmaf(xv.x, kreg[4 * k4 + 0], acc[r]);
                    acc[r] = fmaf(xv.y, kreg[4 * k4 + 1], acc[r]);
                    acc[r] = fmaf(xv.z, kreg[4 * k4 + 2], acc[r]);
                    acc[r] = fmaf(xv.w, kreg[4 * k4 + 3], acc[r]);
                }
            }
            float* zpo = zrow + (size_t)p * RPP * ZN + j;
            #pragma unroll
            for (int r = 0; r < RPP; ++r) zpo[r * ZN] = acc[r];
        }
        if (more) ((float4*)xs[nxt])[threadIdx.x] = gxv;
        __syncthreads();
    }
}

extern "C" void kernel_launch(void* const* d_in, const int* in_sizes, int n_in,
                              void* d_out, int out_size, void* d_ws, size_t ws_size,
                              hipStream_t stream) {
    const float* x    = (const float*)d_in[0];  // [512,1024,128]
    const float* K    = (const float*)d_in[1];  // [128,200]
    const float* R    = (const float*)d_in[2];  // [50,200]
    const float* bias = (const float*)d_in[3];  // [200]
    const float* dw   = (const float*)d_in[4];  // [50,1]
    const float* db   = (const float*)d_in[5];  // [1]
    float* out = (float*)d_out;                 // [512,1]

    const size_t zx_bytes = (size_t)MROWS * ZN * sizeof(float);          // 419.43 MB
    const size_t kt_elems = (size_t)NP * FF;
    const size_t kt_bytes = kt_elems * sizeof(unsigned short);

    if (ws_size >= zx_bytes + 2 * kt_bytes) {
        float* zx = (float*)d_ws;
        unsigned short* kt_hi = (unsigned short*)((char*)d_ws + zx_bytes);
        unsigned short* kt_lo = kt_hi + kt_elems;
        prep_kt_kernel<<<1, 256, 0, stream>>>(K, kt_hi, kt_lo);
        xk_mfma_kernel<<<MROWS / BM, 256, 0, stream>>>(x, kt_hi, kt_lo, bias, zx);
        lstm_scan2_kernel<<<BATCH / 2, 256, 0, stream>>>(zx, R, dw, db, out);
    } else if (ws_size >= zx_bytes) {
        float* zx = (float*)d_ws;
        xk_gemm_kernel<<<BATCH, 256, 0, stream>>>(x, K, bias, zx);
        lstm_scan2_kernel<<<BATCH / 2, 256, 0, stream>>>(zx, R, dw, db, out);
    }
}